// Round 5
// baseline (603.197 us; speedup 1.0000x reference)
//
#include <hip/hip_runtime.h>

#define EDIM 10
#define TDIM 50
#define BATCH 65536
#define CPL 3            // cols per lane (E padded to 12 = 4 lanes x 3 cols)

// Collapsed weights, padded to 12 cols (cols 10,11 zero):
//   g_A[g][k][j] = (Wi_g @ Ws_g)[k][j]      g: 0=r, 1=z, 2=h
//   g_B[g][k][j] = (Wh_g @ Ws_g)[k][j]
//   g_b[g][j]    = (bi_g @ Ws_g + bs_g)[j]
__device__ __align__(16) float g_A[3][10][12];
__device__ __align__(16) float g_B[3][10][12];
__device__ __align__(16) float g_b[3][12];

__device__ __forceinline__ float fast_sigmoid(float x) {
    float e = __expf(-x);
    return __builtin_amdgcn_rcpf(1.0f + e);
}
__device__ __forceinline__ float fast_tanh(float x) {
    float e = __expf(2.0f * x);
    return 1.0f - 2.0f * __builtin_amdgcn_rcpf(e + 1.0f);
}

__global__ void collapse_weights(
    const float* __restrict__ Wi_r, const float* __restrict__ bi_r,
    const float* __restrict__ Wh_r, const float* __restrict__ Ws_r, const float* __restrict__ bs_r,
    const float* __restrict__ Wi_z, const float* __restrict__ bi_z,
    const float* __restrict__ Wh_z, const float* __restrict__ Ws_z, const float* __restrict__ bs_z,
    const float* __restrict__ Wi_h, const float* __restrict__ bi_h,
    const float* __restrict__ Wh_h, const float* __restrict__ Wt_h, const float* __restrict__ bt_h)
{
    for (int s = threadIdx.x; s < 756; s += 256) {
        float v = 0.0f;
        if (s < 720) {
            int kind = s / 360;                 // 0 = A (input path), 1 = B (hidden path)
            int q = s % 360;
            int g = q / 120, k = (q % 120) / 12, j = q % 12;
            if (j < 10) {
                const float* Ws = (g == 0) ? Ws_r : (g == 1) ? Ws_z : Wt_h;
                const float* M  = (kind == 0)
                    ? ((g == 0) ? Wi_r : (g == 1) ? Wi_z : Wi_h)
                    : ((g == 0) ? Wh_r : (g == 1) ? Wh_z : Wh_h);
                #pragma unroll
                for (int jj = 0; jj < 10; jj++) v += M[k * 10 + jj] * Ws[jj * 10 + j];
            }
            if (kind == 0) g_A[g][k][j] = v; else g_B[g][k][j] = v;
        } else {
            int q = s - 720;
            int g = q / 12, j = q % 12;
            if (j < 10) {
                const float* Ws = (g == 0) ? Ws_r : (g == 1) ? Ws_z : Wt_h;
                const float* bi = (g == 0) ? bi_r : (g == 1) ? bi_z : bi_h;
                const float* bs = (g == 0) ? bs_r : (g == 1) ? bs_z : bt_h;
                v = bs[j];
                #pragma unroll
                for (int jj = 0; jj < 10; jj++) v += bi[jj] * Ws[jj * 10 + j];
            }
            g_b[g][j] = v;
        }
    }
}

__global__ __launch_bounds__(256, 2) void augru_main(
    const float* __restrict__ x_all, const float* __restrict__ a_all,
    const float* __restrict__ h0,
    float* __restrict__ out)
{
    const int lane = threadIdx.x & 63;
    const int wv   = threadIdx.x >> 6;
    const int q    = lane & 3;                    // which col-quarter of the row
    const int rl   = lane >> 2;                   // row within wave [0,16)
    const int row  = (blockIdx.x * 4 + wv) * 16 + rl;
    const int c0   = q * CPL;                     // first owned col (0,3,6,9)

    // ---- all weights arch-VGPR-resident: 90 + 90 + 9 = 189 regs, loaded once ----
    float wA[3][10][CPL], wB[3][10][CPL], wb[3][CPL];
    #pragma unroll
    for (int g = 0; g < 3; g++) {
        #pragma unroll
        for (int k = 0; k < 10; k++)
            #pragma unroll
            for (int j = 0; j < CPL; j++) {
                wA[g][k][j] = g_A[g][k][c0 + j];
                wB[g][k][j] = g_B[g][k][c0 + j];
            }
        #pragma unroll
        for (int j = 0; j < CPL; j++) wb[g][j] = g_b[g][c0 + j];
    }

    const float2* xp2 = (const float2*)(x_all + (size_t)row * (TDIM * EDIM));
    const float*  ap  = a_all + (size_t)row * (TDIM * EDIM);

    // clamped own-col indices (q=3 cols 10,11 -> read col 9; values unused downstream)
    int aco[CPL];
    #pragma unroll
    for (int j = 0; j < CPL; j++) aco[j] = (c0 + j < 10) ? (c0 + j) : 9;

    float hown[CPL];
    #pragma unroll
    for (int j = 0; j < CPL; j++) hown[j] = h0[aco[j]];

    const int pbase = (lane & ~3) * 4;            // ds_bpermute byte base of this row's lane group

    float xc[10], acv[CPL];
    #pragma unroll
    for (int i = 0; i < 5; i++) { float2 v = xp2[i]; xc[2 * i] = v.x; xc[2 * i + 1] = v.y; }
    #pragma unroll
    for (int j = 0; j < CPL; j++) acv[j] = ap[aco[j]];

    #pragma unroll 1
    for (int t = 0; t < TDIM; t++) {
        // gather full h[0..9] from this row's 4 lanes (wave-synchronous, no barrier)
        float hf[10];
        #pragma unroll
        for (int k = 0; k < 10; k++)
            hf[k] = __int_as_float(__builtin_amdgcn_ds_bpermute(
                        pbase + (k / 3) * 4, __float_as_int(hown[k % 3])));

        // branchless 1-step-lookahead prefetch (clamped)
        int tn = (t < TDIM - 1) ? (t + 1) : t;
        float xn[10], an[CPL];
        #pragma unroll
        for (int i = 0; i < 5; i++) {
            float2 v = xp2[tn * 5 + i]; xn[2 * i] = v.x; xn[2 * i + 1] = v.y;
        }
        #pragma unroll
        for (int j = 0; j < CPL; j++) an[j] = ap[tn * 10 + aco[j]];

        float ur[CPL], uz[CPL], uh[CPL];
        #pragma unroll
        for (int j = 0; j < CPL; j++) { ur[j] = wb[0][j]; uz[j] = wb[1][j]; uh[j] = wb[2][j]; }

        // x-path: 90 FMAs, all operands in VGPRs
        #pragma unroll
        for (int k = 0; k < 10; k++) {
            float xk = xc[k];
            #pragma unroll
            for (int j = 0; j < CPL; j++) {
                ur[j] = fmaf(xk, wA[0][k][j], ur[j]);
                uz[j] = fmaf(xk, wA[1][k][j], uz[j]);
                uh[j] = fmaf(xk, wA[2][k][j], uh[j]);
            }
        }
        // recurrence path r,z: 60 FMAs
        #pragma unroll
        for (int k = 0; k < 10; k++) {
            float hk = hf[k];
            #pragma unroll
            for (int j = 0; j < CPL; j++) {
                ur[j] = fmaf(hk, wB[0][k][j], ur[j]);
                uz[j] = fmaf(hk, wB[1][k][j], uz[j]);
            }
        }

        float hzo[CPL];
        #pragma unroll
        for (int j = 0; j < CPL; j++) hzo[j] = hown[j] * fast_sigmoid(uz[j]);

        // gather full h*z[0..9]
        float hzf[10];
        #pragma unroll
        for (int k = 0; k < 10; k++)
            hzf[k] = __int_as_float(__builtin_amdgcn_ds_bpermute(
                         pbase + (k / 3) * 4, __float_as_int(hzo[k % 3])));

        // recurrence path h-candidate: 30 FMAs
        #pragma unroll
        for (int k = 0; k < 10; k++) {
            float hk = hzf[k];
            #pragma unroll
            for (int j = 0; j < CPL; j++) uh[j] = fmaf(hk, wB[2][k][j], uh[j]);
        }

        #pragma unroll
        for (int j = 0; j < CPL; j++) {
            float r  = fast_sigmoid(ur[j]);
            float hc = fast_tanh(uh[j]);
            float Ra = acv[j] * r;
            hown[j] = fmaf(Ra, hc - hown[j], hown[j]);
        }

        #pragma unroll
        for (int i = 0; i < 10; i++) xc[i] = xn[i];
        #pragma unroll
        for (int j = 0; j < CPL; j++) acv[j] = an[j];
    }

    // store own real cols (q=3 stores only col 9); once, divergence negligible
    float* orow = out + (size_t)row * EDIM;
    #pragma unroll
    for (int j = 0; j < CPL; j++)
        if (c0 + j < 10) orow[c0 + j] = hown[j];
}

extern "C" void kernel_launch(void* const* d_in, const int* in_sizes, int n_in,
                              void* d_out, int out_size, void* d_ws, size_t ws_size,
                              hipStream_t stream) {
    collapse_weights<<<1, 256, 0, stream>>>(
        (const float*)d_in[3],  (const float*)d_in[4],  (const float*)d_in[5],
        (const float*)d_in[6],  (const float*)d_in[7],
        (const float*)d_in[8],  (const float*)d_in[9],  (const float*)d_in[10],
        (const float*)d_in[11], (const float*)d_in[12],
        (const float*)d_in[13], (const float*)d_in[14], (const float*)d_in[15],
        (const float*)d_in[16], (const float*)d_in[17]);
    augru_main<<<BATCH / 64, 256, 0, stream>>>(
        (const float*)d_in[0], (const float*)d_in[1], (const float*)d_in[2],
        (float*)d_out);
}